// Round 2
// baseline (905.847 us; speedup 1.0000x reference)
//
#include <hip/hip_runtime.h>
#include <hip/hip_bf16.h>

typedef unsigned short ushort_t;
typedef __attribute__((ext_vector_type(8))) short short8;
typedef __attribute__((ext_vector_type(4))) float float4_t;
typedef __attribute__((ext_vector_type(2))) float float2_t;

#define BB 64
#define SS 1024
#define EE 512
#define DD 512
#define AA 512
#define MM (BB*SS)
#define KK 512
#define BM 128
#define BN 128
#define BK 32

__device__ __forceinline__ float bf2f(ushort_t u) {
    return __uint_as_float(((unsigned int)u) << 16);
}
__device__ __forceinline__ ushort_t f2bf(float f) {
    unsigned int u = __float_as_uint(f);
    unsigned int r = u + 0x7fffu + ((u >> 16) & 1u);
    return (ushort_t)(r >> 16);
}
__device__ __forceinline__ float ldmix(int f32, const void* p, long idx) {
    return f32 ? ((const float*)p)[idx] : bf2f(((const ushort_t*)p)[idx]);
}
__device__ __forceinline__ void stmix(int f32, void* p, long idx, float v) {
    if (f32) ((float*)p)[idx] = v;
    else     ((ushort_t*)p)[idx] = f2bf(v);
}

__global__ void k_detect(const ushort_t* __restrict__ enc, int* __restrict__ flag) {
    __shared__ int cnt;
    int tid = threadIdx.x;
    if (tid == 0) cnt = 0;
    __syncthreads();
    int c = 0;
    for (int i = tid; i < 65536; i += 256) {
        unsigned int e = (enc[i] >> 7) & 0xFFu;
        if (e == 0xFFu) c++;
    }
    atomicAdd(&cnt, c);
    __syncthreads();
    if (tid == 0) *flag = (cnt > 0) ? 1 : 0;
}

__global__ void k_proj_dec(const void* __restrict__ dec,
                           const void* __restrict__ Wdec,
                           const int* __restrict__ flagp,
                           float* __restrict__ proj) {
    __shared__ float x[DD];
    const int f32 = *flagp;
    int b = blockIdx.x, tid = threadIdx.x;
    x[tid]       = ldmix(f32, dec, (long)b * DD + tid);
    x[tid + 256] = ldmix(f32, dec, (long)b * DD + tid + 256);
    __syncthreads();
    for (int a = tid; a < AA; a += 256) {
        float acc = 0.f;
        #pragma unroll 8
        for (int k = 0; k < DD; k++)
            acc += x[k] * ldmix(f32, Wdec, (long)a * DD + k);
        proj[b * AA + a] = acc;
    }
}

__device__ __forceinline__ void stage8(int f32, const void* g, long row, int col,
                                       ushort_t* lds) {
    if (f32) {
        const float* gf = (const float*)g + row * KK + col;
        float4_t v0 = *(const float4_t*)(gf);
        float4_t v1 = *(const float4_t*)(gf + 4);
        short8 p;
        p[0] = (short)f2bf(v0[0]); p[1] = (short)f2bf(v0[1]);
        p[2] = (short)f2bf(v0[2]); p[3] = (short)f2bf(v0[3]);
        p[4] = (short)f2bf(v1[0]); p[5] = (short)f2bf(v1[1]);
        p[6] = (short)f2bf(v1[2]); p[7] = (short)f2bf(v1[3]);
        *(short8*)lds = p;
    } else {
        const ushort_t* gb = (const ushort_t*)g + row * KK + col;
        *(short8*)lds = *(const short8*)gb;
    }
}

__global__ __launch_bounds__(256)
void k_gemm1(const void* __restrict__ Xg,
             const void* __restrict__ Bg,
             const float* __restrict__ proj_dec,
             const void* __restrict__ cov,
             const void* __restrict__ Wcov,
             const int* __restrict__ flagp,
             ushort_t* __restrict__ feats) {
    __shared__ ushort_t As[BM * BK];
    __shared__ ushort_t Bs[BN * BK];
    const int f32 = *flagp;
    const int tid = threadIdx.x;
    const int lane = tid & 63, wave = tid >> 6;
    const int quad = lane >> 4, l16 = lane & 15;
    const int wm = wave >> 1, wn = wave & 1;
    const int m0 = blockIdx.y * BM, n0 = blockIdx.x * BN;

    float4_t acc[4][4];
    #pragma unroll
    for (int i = 0; i < 4; i++)
        #pragma unroll
        for (int j = 0; j < 4; j++) acc[i][j] = (float4_t){0.f, 0.f, 0.f, 0.f};

    const int srow = lane >> 2;
    const int scol = (lane & 3) * 8;
    ushort_t* lA0 = &As[(wave * 32 + srow) * BK + scol];
    ushort_t* lB0 = &Bs[(wave * 32 + srow) * BK + scol];

    for (int kt = 0; kt < KK; kt += BK) {
        __syncthreads();
        stage8(f32, Xg, (long)(m0 + wave * 32 + srow), kt + scol, lA0);
        stage8(f32, Xg, (long)(m0 + wave * 32 + srow + 16), kt + scol, lA0 + 16 * BK);
        stage8(f32, Bg, (long)(n0 + wave * 32 + srow), kt + scol, lB0);
        stage8(f32, Bg, (long)(n0 + wave * 32 + srow + 16), kt + scol, lB0 + 16 * BK);
        __syncthreads();
        short8 af[4], bfr[4];
        #pragma unroll
        for (int mt = 0; mt < 4; mt++)
            af[mt] = *(const short8*)&As[(wm * 64 + mt * 16 + l16) * BK + quad * 8];
        #pragma unroll
        for (int nt = 0; nt < 4; nt++)
            bfr[nt] = *(const short8*)&Bs[(wn * 64 + nt * 16 + l16) * BK + quad * 8];
        #pragma unroll
        for (int mt = 0; mt < 4; mt++)
            #pragma unroll
            for (int nt = 0; nt < 4; nt++)
                acc[mt][nt] = __builtin_amdgcn_mfma_f32_16x16x32_bf16(af[mt], bfr[nt], acc[mt][nt], 0, 0, 0);
    }

    #pragma unroll
    for (int mt = 0; mt < 4; mt++) {
        #pragma unroll
        for (int r = 0; r < 4; r++) {
            int m = m0 + wm * 64 + mt * 16 + quad * 4 + r;
            int b = m >> 10;
            float covv = ldmix(f32, cov, m);
            #pragma unroll
            for (int nt = 0; nt < 4; nt++) {
                int n = n0 + wn * 64 + nt * 16 + l16;
                float v = acc[mt][nt][r] + proj_dec[b * AA + n] + covv * ldmix(f32, Wcov, n);
                feats[(size_t)m * AA + n] = f2bf(tanhf(v));
            }
        }
    }
}

__global__ __launch_bounds__(256)
void k_gemm2(const ushort_t* __restrict__ Xg,
             const void* __restrict__ Bg,
             const void* __restrict__ b1,
             const void* __restrict__ wattn,
             const int* __restrict__ flagp,
             float* __restrict__ scores) {
    __shared__ ushort_t As[BM * BK];
    __shared__ ushort_t Bs[BN * BK];
    const int f32 = *flagp;
    const int tid = threadIdx.x;
    const int lane = tid & 63, wave = tid >> 6;
    const int quad = lane >> 4, l16 = lane & 15;
    const int wm = wave >> 1, wn = wave & 1;
    const int m0 = blockIdx.y * BM, n0 = blockIdx.x * BN;

    float4_t acc[4][4];
    #pragma unroll
    for (int i = 0; i < 4; i++)
        #pragma unroll
        for (int j = 0; j < 4; j++) acc[i][j] = (float4_t){0.f, 0.f, 0.f, 0.f};

    const int srow = lane >> 2;
    const int scol = (lane & 3) * 8;
    ushort_t* lA0 = &As[(wave * 32 + srow) * BK + scol];
    ushort_t* lB0 = &Bs[(wave * 32 + srow) * BK + scol];

    for (int kt = 0; kt < KK; kt += BK) {
        __syncthreads();
        stage8(0,   Xg, (long)(m0 + wave * 32 + srow), kt + scol, lA0);
        stage8(0,   Xg, (long)(m0 + wave * 32 + srow + 16), kt + scol, lA0 + 16 * BK);
        stage8(f32, Bg, (long)(n0 + wave * 32 + srow), kt + scol, lB0);
        stage8(f32, Bg, (long)(n0 + wave * 32 + srow + 16), kt + scol, lB0 + 16 * BK);
        __syncthreads();
        short8 af[4], bfr[4];
        #pragma unroll
        for (int mt = 0; mt < 4; mt++)
            af[mt] = *(const short8*)&As[(wm * 64 + mt * 16 + l16) * BK + quad * 8];
        #pragma unroll
        for (int nt = 0; nt < 4; nt++)
            bfr[nt] = *(const short8*)&Bs[(wn * 64 + nt * 16 + l16) * BK + quad * 8];
        #pragma unroll
        for (int mt = 0; mt < 4; mt++)
            #pragma unroll
            for (int nt = 0; nt < 4; nt++)
                acc[mt][nt] = __builtin_amdgcn_mfma_f32_16x16x32_bf16(af[mt], bfr[nt], acc[mt][nt], 0, 0, 0);
    }

    float wv[4], bv[4];
    #pragma unroll
    for (int nt = 0; nt < 4; nt++) {
        int n = n0 + wn * 64 + nt * 16 + l16;
        wv[nt] = ldmix(f32, wattn, n);
        bv[nt] = ldmix(f32, b1, n);
    }
    #pragma unroll
    for (int mt = 0; mt < 4; mt++) {
        #pragma unroll
        for (int r = 0; r < 4; r++) {
            int m = m0 + wm * 64 + mt * 16 + quad * 4 + r;
            float s = 0.f;
            #pragma unroll
            for (int nt = 0; nt < 4; nt++) {
                int n = n0 + wn * 64 + nt * 16 + l16;
                float v = acc[mt][nt][r] + bv[nt] + bf2f(Xg[(size_t)m * AA + n]);
                s += tanhf(v) * wv[nt];
            }
            s += __shfl_xor(s, 1);
            s += __shfl_xor(s, 2);
            s += __shfl_xor(s, 4);
            s += __shfl_xor(s, 8);
            if (l16 == 0) atomicAdd(&scores[m], s);
        }
    }
}

__global__ void k_softmax(const float* __restrict__ scores,
                          const int* __restrict__ mask,
                          const void* __restrict__ cov,
                          const int* __restrict__ flagp,
                          float* __restrict__ attnw,
                          void* __restrict__ dout) {
    __shared__ float red[4];
    const int f32 = *flagp;
    int b = blockIdx.x, tid = threadIdx.x;
    float v[4];
    #pragma unroll
    for (int i = 0; i < 4; i++) {
        int s = tid + i * 256;
        float sc = scores[b * SS + s];
        if (mask[b * SS + s] == 0) sc = -1e9f;
        v[i] = sc;
    }
    float mx = fmaxf(fmaxf(v[0], v[1]), fmaxf(v[2], v[3]));
    #pragma unroll
    for (int off = 1; off < 64; off <<= 1) mx = fmaxf(mx, __shfl_xor(mx, off));
    if ((tid & 63) == 0) red[tid >> 6] = mx;
    __syncthreads();
    mx = fmaxf(fmaxf(red[0], red[1]), fmaxf(red[2], red[3]));
    __syncthreads();
    float e[4], sum = 0.f;
    #pragma unroll
    for (int i = 0; i < 4; i++) { e[i] = expf(v[i] - mx); sum += e[i]; }
    #pragma unroll
    for (int off = 1; off < 64; off <<= 1) sum += __shfl_xor(sum, off);
    if ((tid & 63) == 0) red[tid >> 6] = sum;
    __syncthreads();
    sum = red[0] + red[1] + red[2] + red[3];
    float inv = 1.0f / sum;
    #pragma unroll
    for (int i = 0; i < 4; i++) {
        int s = tid + i * 256;
        float w = e[i] * inv;
        attnw[b * SS + s] = w;
        stmix(f32, dout, 32768L + (long)b * SS + s, w);
        stmix(f32, dout, 98304L + (long)b * SS + s, ldmix(f32, cov, (long)b * SS + s) + w);
    }
}

__global__ void k_context(const void* __restrict__ enc,
                          const float* __restrict__ attnw,
                          const int* __restrict__ flagp,
                          float* __restrict__ ctx) {
    const int f32 = *flagp;
    int b = blockIdx.x, sc = blockIdx.y;
    int tid = threadIdx.x;
    float a0 = 0.f, a1 = 0.f;
    const float* wrow = attnw + b * SS + sc * 128;
    if (f32) {
        const float* base = (const float*)enc + ((size_t)b * SS + sc * 128) * EE;
        for (int s = 0; s < 128; s++) {
            float w = wrow[s];
            float2_t u = *(const float2_t*)(base + (size_t)s * EE + 2 * tid);
            a0 += w * u[0];
            a1 += w * u[1];
        }
    } else {
        const unsigned int* base = (const unsigned int*)enc + ((size_t)b * SS + sc * 128) * (EE / 2);
        for (int s = 0; s < 128; s++) {
            float w = wrow[s];
            unsigned int u = base[(size_t)s * (EE / 2) + tid];
            a0 += w * bf2f((ushort_t)(u & 0xffff));
            a1 += w * bf2f((ushort_t)(u >> 16));
        }
    }
    atomicAdd(&ctx[b * EE + 2 * tid], a0);
    atomicAdd(&ctx[b * EE + 2 * tid + 1], a1);
}

__global__ void k_gate(const float* __restrict__ ctx,
                       const void* __restrict__ dec,
                       const void* __restrict__ Wg,
                       const void* __restrict__ bg,
                       const int* __restrict__ flagp,
                       void* __restrict__ dout) {
    __shared__ float gin[EE + DD];
    const int f32 = *flagp;
    int b = blockIdx.x, tid = threadIdx.x;
    gin[2 * tid]     = ctx[b * EE + 2 * tid];
    gin[2 * tid + 1] = ctx[b * EE + 2 * tid + 1];
    gin[EE + tid]       = ldmix(f32, dec, (long)b * DD + tid);
    gin[EE + tid + 256] = ldmix(f32, dec, (long)b * DD + tid + 256);
    __syncthreads();
    for (int a = tid; a < AA; a += 256) {
        float acc = ldmix(f32, bg, a);
        #pragma unroll 8
        for (int k = 0; k < EE + DD; k++)
            acc += gin[k] * ldmix(f32, Wg, (long)a * (EE + DD) + k);
        float g = 1.f / (1.f + expf(-acc));
        stmix(f32, dout, (long)b * AA + a, g * ctx[b * EE + a]);
    }
}

extern "C" void kernel_launch(void* const* d_in, const int* in_sizes, int n_in,
                              void* d_out, int out_size, void* d_ws, size_t ws_size,
                              hipStream_t stream) {
    const void* enc   = d_in[0];
    const void* dec   = d_in[1];
    const int*  mask  = (const int*)d_in[2];
    const void* cov   = d_in[3];
    const void* Wenc  = d_in[4];
    const void* Wdec  = d_in[5];
    const void* wattn = d_in[6];
    const void* Wl1   = d_in[7];
    const void* b1    = d_in[8];
    const void* Wcov  = d_in[9];
    const void* Wg    = d_in[10];
    const void* bg    = d_in[11];

    char* ws = (char*)d_ws;
    float*    scores = (float*)ws;                 // 262144 B
    float*    ctx    = (float*)(ws + 262144);      // 131072 B
    float*    attnw  = (float*)(ws + 393216);      // 262144 B
    float*    projd  = (float*)(ws + 655360);      // 131072 B
    int*      flag   = (int*)(ws + 786432);        // 4 B
    ushort_t* feats  = (ushort_t*)(ws + 1048576);  // 67108864 B

    hipMemsetAsync(ws, 0, 393216, stream);
    k_detect<<<1, 256, 0, stream>>>((const ushort_t*)enc, flag);
    k_proj_dec<<<BB, 256, 0, stream>>>(dec, Wdec, flag, projd);
    k_gemm1<<<dim3(AA / BN, MM / BM), 256, 0, stream>>>(enc, Wenc, projd, cov, Wcov, flag, feats);
    k_gemm2<<<dim3(AA / BN, MM / BM), 256, 0, stream>>>(feats, Wl1, b1, wattn, flag, scores);
    k_softmax<<<BB, 256, 0, stream>>>(scores, mask, cov, flag, attnw, d_out);
    k_context<<<dim3(BB, 8), 256, 0, stream>>>(enc, attnw, flag, ctx);
    k_gate<<<BB, 256, 0, stream>>>(ctx, dec, Wg, bg, flag, d_out);
}

// Round 4
// 592.530 us; speedup vs baseline: 1.5288x; 1.5288x over previous
//
#include <hip/hip_runtime.h>
#include <hip/hip_bf16.h>

typedef unsigned short ushort_t;
typedef __attribute__((ext_vector_type(8))) short short8;
typedef __attribute__((ext_vector_type(4))) float float4_t;
typedef __attribute__((ext_vector_type(2))) float float2_t;

#define BB 64
#define SS 1024
#define EE 512
#define DD 512
#define AA 512
#define MM (BB*SS)
#define KK 512
#define BM 128
#define BN 128
#define BK 32

__device__ __forceinline__ float bf2f(ushort_t u) {
    return __uint_as_float(((unsigned int)u) << 16);
}
__device__ __forceinline__ ushort_t f2bf(float f) {
    unsigned int u = __float_as_uint(f);
    unsigned int r = u + 0x7fffu + ((u >> 16) & 1u);
    return (ushort_t)(r >> 16);
}
__device__ __forceinline__ float ldmix(int f32, const void* p, long idx) {
    return f32 ? ((const float*)p)[idx] : bf2f(((const ushort_t*)p)[idx]);
}
__device__ __forceinline__ void stmix(int f32, void* p, long idx, float v) {
    if (f32) ((float*)p)[idx] = v;
    else     ((ushort_t*)p)[idx] = f2bf(v);
}

__global__ void k_detect(const ushort_t* __restrict__ enc, int* __restrict__ flag) {
    __shared__ int cnt;
    int tid = threadIdx.x;
    if (tid == 0) cnt = 0;
    __syncthreads();
    int c = 0;
    for (int i = tid; i < 65536; i += 256) {
        unsigned int e = (enc[i] >> 7) & 0xFFu;
        if (e == 0xFFu) c++;
    }
    atomicAdd(&cnt, c);
    __syncthreads();
    if (tid == 0) *flag = (cnt > 0) ? 1 : 0;
}

// ---------------- proj_dec: wave-per-output. grid (A/4, B), 256 thr ----------------
__global__ __launch_bounds__(256)
void k_proj_dec(const void* __restrict__ dec,
                const void* __restrict__ Wdec,
                const int* __restrict__ flagp,
                float* __restrict__ proj) {
    __shared__ float x[DD];
    const int f32 = *flagp;
    const int b = blockIdx.y;
    const int tid = threadIdx.x, lane = tid & 63, wave = tid >> 6;
    x[tid]       = ldmix(f32, dec, (long)b * DD + tid);
    x[tid + 256] = ldmix(f32, dec, (long)b * DD + tid + 256);
    __syncthreads();
    const int a = blockIdx.x * 4 + wave;
    float s = 0.f;
    if (f32) {
        const float* wr = (const float*)Wdec + (size_t)a * DD + lane * 8;
        #pragma unroll
        for (int j = 0; j < 8; j++) s += wr[j] * x[lane * 8 + j];
    } else {
        const ushort_t* wr = (const ushort_t*)Wdec + (size_t)a * DD + lane * 8;
        short8 w = *(const short8*)wr;
        #pragma unroll
        for (int j = 0; j < 8; j++) s += bf2f((ushort_t)w[j]) * x[lane * 8 + j];
    }
    #pragma unroll
    for (int off = 1; off < 64; off <<= 1) s += __shfl_xor(s, off);
    if (lane == 0) proj[b * AA + a] = s;
}

__device__ __forceinline__ void stage8(int f32, const void* g, long row, int col,
                                       ushort_t* lds) {
    if (f32) {
        const float* gf = (const float*)g + row * KK + col;
        float4_t v0 = *(const float4_t*)(gf);
        float4_t v1 = *(const float4_t*)(gf + 4);
        short8 p;
        p[0] = (short)f2bf(v0[0]); p[1] = (short)f2bf(v0[1]);
        p[2] = (short)f2bf(v0[2]); p[3] = (short)f2bf(v0[3]);
        p[4] = (short)f2bf(v1[0]); p[5] = (short)f2bf(v1[1]);
        p[6] = (short)f2bf(v1[2]); p[7] = (short)f2bf(v1[3]);
        *(short8*)lds = p;
    } else {
        const ushort_t* gb = (const ushort_t*)g + row * KK + col;
        *(short8*)lds = *(const short8*)gb;
    }
}

__global__ __launch_bounds__(256)
void k_gemm1(const void* __restrict__ Xg,
             const void* __restrict__ Bg,
             const float* __restrict__ proj_dec,
             const void* __restrict__ cov,
             const void* __restrict__ Wcov,
             const int* __restrict__ flagp,
             ushort_t* __restrict__ feats) {
    __shared__ ushort_t As[BM * BK];
    __shared__ ushort_t Bs[BN * BK];
    const int f32 = *flagp;
    const int tid = threadIdx.x;
    const int lane = tid & 63, wave = tid >> 6;
    const int quad = lane >> 4, l16 = lane & 15;
    const int wm = wave >> 1, wn = wave & 1;
    const int m0 = blockIdx.y * BM, n0 = blockIdx.x * BN;

    float4_t acc[4][4];
    #pragma unroll
    for (int i = 0; i < 4; i++)
        #pragma unroll
        for (int j = 0; j < 4; j++) acc[i][j] = (float4_t){0.f, 0.f, 0.f, 0.f};

    const int srow = lane >> 2;
    const int scol = (lane & 3) * 8;
    ushort_t* lA0 = &As[(wave * 32 + srow) * BK + scol];
    ushort_t* lB0 = &Bs[(wave * 32 + srow) * BK + scol];

    for (int kt = 0; kt < KK; kt += BK) {
        __syncthreads();
        stage8(f32, Xg, (long)(m0 + wave * 32 + srow), kt + scol, lA0);
        stage8(f32, Xg, (long)(m0 + wave * 32 + srow + 16), kt + scol, lA0 + 16 * BK);
        stage8(f32, Bg, (long)(n0 + wave * 32 + srow), kt + scol, lB0);
        stage8(f32, Bg, (long)(n0 + wave * 32 + srow + 16), kt + scol, lB0 + 16 * BK);
        __syncthreads();
        short8 af[4], bfr[4];
        #pragma unroll
        for (int mt = 0; mt < 4; mt++)
            af[mt] = *(const short8*)&As[(wm * 64 + mt * 16 + l16) * BK + quad * 8];
        #pragma unroll
        for (int nt = 0; nt < 4; nt++)
            bfr[nt] = *(const short8*)&Bs[(wn * 64 + nt * 16 + l16) * BK + quad * 8];
        #pragma unroll
        for (int mt = 0; mt < 4; mt++)
            #pragma unroll
            for (int nt = 0; nt < 4; nt++)
                acc[mt][nt] = __builtin_amdgcn_mfma_f32_16x16x32_bf16(af[mt], bfr[nt], acc[mt][nt], 0, 0, 0);
    }

    #pragma unroll
    for (int mt = 0; mt < 4; mt++) {
        #pragma unroll
        for (int r = 0; r < 4; r++) {
            int m = m0 + wm * 64 + mt * 16 + quad * 4 + r;
            int b = m >> 10;
            float covv = ldmix(f32, cov, m);
            #pragma unroll
            for (int nt = 0; nt < 4; nt++) {
                int n = n0 + wn * 64 + nt * 16 + l16;
                float v = acc[mt][nt][r] + proj_dec[b * AA + n] + covv * ldmix(f32, Wcov, n);
                feats[(size_t)m * AA + n] = f2bf(tanhf(v));
            }
        }
    }
}

__global__ __launch_bounds__(256)
void k_gemm2(const ushort_t* __restrict__ Xg,
             const void* __restrict__ Bg,
             const void* __restrict__ b1,
             const void* __restrict__ wattn,
             const int* __restrict__ flagp,
             float* __restrict__ scores) {
    __shared__ ushort_t As[BM * BK];
    __shared__ ushort_t Bs[BN * BK];
    const int f32 = *flagp;
    const int tid = threadIdx.x;
    const int lane = tid & 63, wave = tid >> 6;
    const int quad = lane >> 4, l16 = lane & 15;
    const int wm = wave >> 1, wn = wave & 1;
    const int m0 = blockIdx.y * BM, n0 = blockIdx.x * BN;

    float4_t acc[4][4];
    #pragma unroll
    for (int i = 0; i < 4; i++)
        #pragma unroll
        for (int j = 0; j < 4; j++) acc[i][j] = (float4_t){0.f, 0.f, 0.f, 0.f};

    const int srow = lane >> 2;
    const int scol = (lane & 3) * 8;
    ushort_t* lA0 = &As[(wave * 32 + srow) * BK + scol];
    ushort_t* lB0 = &Bs[(wave * 32 + srow) * BK + scol];

    for (int kt = 0; kt < KK; kt += BK) {
        __syncthreads();
        stage8(0,   Xg, (long)(m0 + wave * 32 + srow), kt + scol, lA0);
        stage8(0,   Xg, (long)(m0 + wave * 32 + srow + 16), kt + scol, lA0 + 16 * BK);
        stage8(f32, Bg, (long)(n0 + wave * 32 + srow), kt + scol, lB0);
        stage8(f32, Bg, (long)(n0 + wave * 32 + srow + 16), kt + scol, lB0 + 16 * BK);
        __syncthreads();
        short8 af[4], bfr[4];
        #pragma unroll
        for (int mt = 0; mt < 4; mt++)
            af[mt] = *(const short8*)&As[(wm * 64 + mt * 16 + l16) * BK + quad * 8];
        #pragma unroll
        for (int nt = 0; nt < 4; nt++)
            bfr[nt] = *(const short8*)&Bs[(wn * 64 + nt * 16 + l16) * BK + quad * 8];
        #pragma unroll
        for (int mt = 0; mt < 4; mt++)
            #pragma unroll
            for (int nt = 0; nt < 4; nt++)
                acc[mt][nt] = __builtin_amdgcn_mfma_f32_16x16x32_bf16(af[mt], bfr[nt], acc[mt][nt], 0, 0, 0);
    }

    float wv[4], bv[4];
    #pragma unroll
    for (int nt = 0; nt < 4; nt++) {
        int n = n0 + wn * 64 + nt * 16 + l16;
        wv[nt] = ldmix(f32, wattn, n);
        bv[nt] = ldmix(f32, b1, n);
    }
    #pragma unroll
    for (int mt = 0; mt < 4; mt++) {
        #pragma unroll
        for (int r = 0; r < 4; r++) {
            int m = m0 + wm * 64 + mt * 16 + quad * 4 + r;
            float s = 0.f;
            #pragma unroll
            for (int nt = 0; nt < 4; nt++) {
                int n = n0 + wn * 64 + nt * 16 + l16;
                float v = acc[mt][nt][r] + bv[nt] + bf2f(Xg[(size_t)m * AA + n]);
                s += tanhf(v) * wv[nt];
            }
            s += __shfl_xor(s, 1);
            s += __shfl_xor(s, 2);
            s += __shfl_xor(s, 4);
            s += __shfl_xor(s, 8);
            if (l16 == 0) atomicAdd(&scores[m], s);
        }
    }
}

__global__ void k_softmax(const float* __restrict__ scores,
                          const int* __restrict__ mask,
                          const void* __restrict__ cov,
                          const int* __restrict__ flagp,
                          float* __restrict__ attnw,
                          void* __restrict__ dout) {
    __shared__ float red[4];
    const int f32 = *flagp;
    int b = blockIdx.x, tid = threadIdx.x;
    float v[4];
    #pragma unroll
    for (int i = 0; i < 4; i++) {
        int s = tid + i * 256;
        float sc = scores[b * SS + s];
        if (mask[b * SS + s] == 0) sc = -1e9f;
        v[i] = sc;
    }
    float mx = fmaxf(fmaxf(v[0], v[1]), fmaxf(v[2], v[3]));
    #pragma unroll
    for (int off = 1; off < 64; off <<= 1) mx = fmaxf(mx, __shfl_xor(mx, off));
    if ((tid & 63) == 0) red[tid >> 6] = mx;
    __syncthreads();
    mx = fmaxf(fmaxf(red[0], red[1]), fmaxf(red[2], red[3]));
    __syncthreads();
    float e[4], sum = 0.f;
    #pragma unroll
    for (int i = 0; i < 4; i++) { e[i] = expf(v[i] - mx); sum += e[i]; }
    #pragma unroll
    for (int off = 1; off < 64; off <<= 1) sum += __shfl_xor(sum, off);
    if ((tid & 63) == 0) red[tid >> 6] = sum;
    __syncthreads();
    sum = red[0] + red[1] + red[2] + red[3];
    float inv = 1.0f / sum;
    #pragma unroll
    for (int i = 0; i < 4; i++) {
        int s = tid + i * 256;
        float w = e[i] * inv;
        attnw[b * SS + s] = w;
        stmix(f32, dout, 32768L + (long)b * SS + s, w);
        stmix(f32, dout, 98304L + (long)b * SS + s, ldmix(f32, cov, (long)b * SS + s) + w);
    }
}

__global__ void k_context(const void* __restrict__ enc,
                          const float* __restrict__ attnw,
                          const int* __restrict__ flagp,
                          float* __restrict__ ctx) {
    const int f32 = *flagp;
    int b = blockIdx.x, sc = blockIdx.y;
    int tid = threadIdx.x;
    float a0 = 0.f, a1 = 0.f;
    const float* wrow = attnw + b * SS + sc * 128;
    if (f32) {
        const float* base = (const float*)enc + ((size_t)b * SS + sc * 128) * EE;
        for (int s = 0; s < 128; s++) {
            float w = wrow[s];
            float2_t u = *(const float2_t*)(base + (size_t)s * EE + 2 * tid);
            a0 += w * u[0];
            a1 += w * u[1];
        }
    } else {
        const unsigned int* base = (const unsigned int*)enc + ((size_t)b * SS + sc * 128) * (EE / 2);
        for (int s = 0; s < 128; s++) {
            float w = wrow[s];
            unsigned int u = base[(size_t)s * (EE / 2) + tid];
            a0 += w * bf2f((ushort_t)(u & 0xffff));
            a1 += w * bf2f((ushort_t)(u >> 16));
        }
    }
    atomicAdd(&ctx[b * EE + 2 * tid], a0);
    atomicAdd(&ctx[b * EE + 2 * tid + 1], a1);
}

// ---------------- gate: wave-per-output. grid (A/4, B), 256 thr ----------------
__global__ __launch_bounds__(256)
void k_gate(const float* __restrict__ ctx,
            const void* __restrict__ dec,
            const void* __restrict__ Wg,
            const void* __restrict__ bg,
            const int* __restrict__ flagp,
            void* __restrict__ dout) {
    __shared__ float gin[EE + DD];
    const int f32 = *flagp;
    const int b = blockIdx.y;
    const int tid = threadIdx.x, lane = tid & 63, wave = tid >> 6;
    gin[2 * tid]     = ctx[b * EE + 2 * tid];
    gin[2 * tid + 1] = ctx[b * EE + 2 * tid + 1];
    gin[EE + tid]       = ldmix(f32, dec, (long)b * DD + tid);
    gin[EE + tid + 256] = ldmix(f32, dec, (long)b * DD + tid + 256);
    __syncthreads();
    const int a = blockIdx.x * 4 + wave;
    float s = 0.f;
    if (f32) {
        const float* wr = (const float*)Wg + (size_t)a * (EE + DD) + lane * 16;
        #pragma unroll
        for (int j = 0; j < 16; j++) s += wr[j] * gin[lane * 16 + j];
    } else {
        const ushort_t* wr = (const ushort_t*)Wg + (size_t)a * (EE + DD) + lane * 16;
        short8 w0 = *(const short8*)wr;
        short8 w1 = *(const short8*)(wr + 8);
        #pragma unroll
        for (int j = 0; j < 8; j++) {
            s += bf2f((ushort_t)w0[j]) * gin[lane * 16 + j];
            s += bf2f((ushort_t)w1[j]) * gin[lane * 16 + 8 + j];
        }
    }
    #pragma unroll
    for (int off = 1; off < 64; off <<= 1) s += __shfl_xor(s, off);
    if (lane == 0) {
        float acc = s + ldmix(f32, bg, a);
        float g = 1.f / (1.f + expf(-acc));
        stmix(f32, dout, (long)b * AA + a, g * ctx[b * EE + a]);
    }
}

extern "C" void kernel_launch(void* const* d_in, const int* in_sizes, int n_in,
                              void* d_out, int out_size, void* d_ws, size_t ws_size,
                              hipStream_t stream) {
    const void* enc   = d_in[0];
    const void* dec   = d_in[1];
    const int*  mask  = (const int*)d_in[2];
    const void* cov   = d_in[3];
    const void* Wenc  = d_in[4];
    const void* Wdec  = d_in[5];
    const void* wattn = d_in[6];
    const void* Wl1   = d_in[7];
    const void* b1    = d_in[8];
    const void* Wcov  = d_in[9];
    const void* Wg    = d_in[10];
    const void* bg    = d_in[11];

    char* ws = (char*)d_ws;
    float*    scores = (float*)ws;                 // 262144 B
    float*    ctx    = (float*)(ws + 262144);      // 131072 B
    float*    attnw  = (float*)(ws + 393216);      // 262144 B
    float*    projd  = (float*)(ws + 655360);      // 131072 B
    int*      flag   = (int*)(ws + 786432);        // 4 B
    ushort_t* feats  = (ushort_t*)(ws + 1048576);  // 67108864 B

    hipMemsetAsync(ws, 0, 393216, stream);
    k_detect<<<1, 256, 0, stream>>>((const ushort_t*)enc, flag);
    k_proj_dec<<<dim3(AA / 4, BB), 256, 0, stream>>>(dec, Wdec, flag, projd);
    k_gemm1<<<dim3(AA / BN, MM / BM), 256, 0, stream>>>(enc, Wenc, projd, cov, Wcov, flag, feats);
    k_gemm2<<<dim3(AA / BN, MM / BM), 256, 0, stream>>>(feats, Wl1, b1, wattn, flag, scores);
    k_softmax<<<BB, 256, 0, stream>>>(scores, mask, cov, flag, attnw, d_out);
    k_context<<<dim3(BB, 8), 256, 0, stream>>>(enc, attnw, flag, ctx);
    k_gate<<<dim3(AA / 4, BB), 256, 0, stream>>>(ctx, dec, Wg, bg, flag, d_out);
}

// Round 5
// 514.084 us; speedup vs baseline: 1.7621x; 1.1526x over previous
//
#include <hip/hip_runtime.h>
#include <hip/hip_bf16.h>

typedef unsigned short ushort_t;
typedef __attribute__((ext_vector_type(8))) short short8;
typedef __attribute__((ext_vector_type(4))) float float4_t;
typedef __attribute__((ext_vector_type(2))) float float2_t;
typedef __attribute__((ext_vector_type(4))) unsigned int uint4_t;

#define BB 64
#define SS 1024
#define EE 512
#define DD 512
#define AA 512
#define MM (BB*SS)
#define KK 512
#define BM 128
#define BN 128
#define BK 32
#define BKP 40   // padded LDS row stride (80 B = 20 banks -> 2-way aliasing, free)

__device__ __forceinline__ float bf2f(ushort_t u) {
    return __uint_as_float(((unsigned int)u) << 16);
}
__device__ __forceinline__ ushort_t f2bf(float f) {
    unsigned int u = __float_as_uint(f);
    unsigned int r = u + 0x7fffu + ((u >> 16) & 1u);
    return (ushort_t)(r >> 16);
}
__device__ __forceinline__ float ldmix(int f32, const void* p, long idx) {
    return f32 ? ((const float*)p)[idx] : bf2f(((const ushort_t*)p)[idx]);
}
__device__ __forceinline__ void stmix(int f32, void* p, long idx, float v) {
    if (f32) ((float*)p)[idx] = v;
    else     ((ushort_t*)p)[idx] = f2bf(v);
}
__device__ __forceinline__ float fast_tanh(float x) {
    float e = __expf(2.f * x);
    return 1.f - 2.f / (e + 1.f);   // x>>0: e=inf -> 1; x<<0: e=0 -> -1
}

__global__ void k_detect(const ushort_t* __restrict__ enc, int* __restrict__ flag) {
    __shared__ int cnt;
    int tid = threadIdx.x;
    if (tid == 0) cnt = 0;
    __syncthreads();
    int c = 0;
    const uint4_t* p = (const uint4_t*)enc;   // 65536 ushorts = 4096 uint4
    for (int i = tid; i < 4096; i += 256) {
        uint4_t v = p[i];
        #pragma unroll
        for (int j = 0; j < 4; j++) {
            unsigned int u = v[j];
            if (((u >> 7) & 0xFFu) == 0xFFu || ((u >> 23) & 0xFFu) == 0xFFu) c++;
        }
    }
    atomicAdd(&cnt, c);
    __syncthreads();
    if (tid == 0) *flag = (cnt > 0) ? 1 : 0;
}

// ---------------- proj_dec: wave-per-output. grid (A/4, B), 256 thr ----------------
__global__ __launch_bounds__(256)
void k_proj_dec(const void* __restrict__ dec,
                const void* __restrict__ Wdec,
                const int* __restrict__ flagp,
                float* __restrict__ proj) {
    __shared__ float x[DD];
    const int f32 = *flagp;
    const int b = blockIdx.y;
    const int tid = threadIdx.x, lane = tid & 63, wave = tid >> 6;
    x[tid]       = ldmix(f32, dec, (long)b * DD + tid);
    x[tid + 256] = ldmix(f32, dec, (long)b * DD + tid + 256);
    __syncthreads();
    const int a = blockIdx.x * 4 + wave;
    float s = 0.f;
    if (f32) {
        const float* wr = (const float*)Wdec + (size_t)a * DD + lane * 8;
        #pragma unroll
        for (int j = 0; j < 8; j++) s += wr[j] * x[lane * 8 + j];
    } else {
        const ushort_t* wr = (const ushort_t*)Wdec + (size_t)a * DD + lane * 8;
        short8 w = *(const short8*)wr;
        #pragma unroll
        for (int j = 0; j < 8; j++) s += bf2f((ushort_t)w[j]) * x[lane * 8 + j];
    }
    #pragma unroll
    for (int off = 1; off < 64; off <<= 1) s += __shfl_xor(s, off);
    if (lane == 0) proj[b * AA + a] = s;
}

__device__ __forceinline__ void stage8(int f32, const void* g, long row, int col,
                                       ushort_t* lds) {
    if (f32) {
        const float* gf = (const float*)g + row * KK + col;
        float4_t v0 = *(const float4_t*)(gf);
        float4_t v1 = *(const float4_t*)(gf + 4);
        short8 p;
        p[0] = (short)f2bf(v0[0]); p[1] = (short)f2bf(v0[1]);
        p[2] = (short)f2bf(v0[2]); p[3] = (short)f2bf(v0[3]);
        p[4] = (short)f2bf(v1[0]); p[5] = (short)f2bf(v1[1]);
        p[6] = (short)f2bf(v1[2]); p[7] = (short)f2bf(v1[3]);
        *(short8*)lds = p;
    } else {
        const ushort_t* gb = (const ushort_t*)g + row * KK + col;
        *(short8*)lds = *(const short8*)gb;
    }
}

__global__ __launch_bounds__(256)
void k_gemm1(const void* __restrict__ Xg,
             const void* __restrict__ Bg,
             const float* __restrict__ proj_dec,
             const void* __restrict__ cov,
             const void* __restrict__ Wcov,
             const int* __restrict__ flagp,
             ushort_t* __restrict__ feats) {
    __shared__ ushort_t As[BM * BKP];
    __shared__ ushort_t Bs[BN * BKP];
    const int f32 = *flagp;
    const int tid = threadIdx.x;
    const int lane = tid & 63, wave = tid >> 6;
    const int quad = lane >> 4, l16 = lane & 15;
    const int wm = wave >> 1, wn = wave & 1;
    const int m0 = blockIdx.y * BM, n0 = blockIdx.x * BN;

    float4_t acc[4][4];
    #pragma unroll
    for (int i = 0; i < 4; i++)
        #pragma unroll
        for (int j = 0; j < 4; j++) acc[i][j] = (float4_t){0.f, 0.f, 0.f, 0.f};

    const int srow = lane >> 2;
    const int scol = (lane & 3) * 8;
    ushort_t* lA0 = &As[(wave * 32 + srow) * BKP + scol];
    ushort_t* lB0 = &Bs[(wave * 32 + srow) * BKP + scol];

    for (int kt = 0; kt < KK; kt += BK) {
        __syncthreads();
        stage8(f32, Xg, (long)(m0 + wave * 32 + srow), kt + scol, lA0);
        stage8(f32, Xg, (long)(m0 + wave * 32 + srow + 16), kt + scol, lA0 + 16 * BKP);
        stage8(f32, Bg, (long)(n0 + wave * 32 + srow), kt + scol, lB0);
        stage8(f32, Bg, (long)(n0 + wave * 32 + srow + 16), kt + scol, lB0 + 16 * BKP);
        __syncthreads();
        short8 af[4], bfr[4];
        #pragma unroll
        for (int mt = 0; mt < 4; mt++)
            af[mt] = *(const short8*)&As[(wm * 64 + mt * 16 + l16) * BKP + quad * 8];
        #pragma unroll
        for (int nt = 0; nt < 4; nt++)
            bfr[nt] = *(const short8*)&Bs[(wn * 64 + nt * 16 + l16) * BKP + quad * 8];
        #pragma unroll
        for (int mt = 0; mt < 4; mt++)
            #pragma unroll
            for (int nt = 0; nt < 4; nt++)
                acc[mt][nt] = __builtin_amdgcn_mfma_f32_16x16x32_bf16(af[mt], bfr[nt], acc[mt][nt], 0, 0, 0);
    }

    #pragma unroll
    for (int mt = 0; mt < 4; mt++) {
        #pragma unroll
        for (int r = 0; r < 4; r++) {
            int m = m0 + wm * 64 + mt * 16 + quad * 4 + r;
            int b = m >> 10;
            float covv = ldmix(f32, cov, m);
            #pragma unroll
            for (int nt = 0; nt < 4; nt++) {
                int n = n0 + wn * 64 + nt * 16 + l16;
                float v = acc[mt][nt][r] + proj_dec[b * AA + n] + covv * ldmix(f32, Wcov, n);
                feats[(size_t)m * AA + n] = f2bf(fast_tanh(v));
            }
        }
    }
}

__global__ __launch_bounds__(256)
void k_gemm2(const ushort_t* __restrict__ Xg,
             const void* __restrict__ Bg,
             const void* __restrict__ b1,
             const void* __restrict__ wattn,
             const int* __restrict__ flagp,
             float* __restrict__ scores) {
    __shared__ ushort_t As[BM * BKP];
    __shared__ ushort_t Bs[BN * BKP];
    const int f32 = *flagp;
    const int tid = threadIdx.x;
    const int lane = tid & 63, wave = tid >> 6;
    const int quad = lane >> 4, l16 = lane & 15;
    const int wm = wave >> 1, wn = wave & 1;
    const int m0 = blockIdx.y * BM, n0 = blockIdx.x * BN;

    float4_t acc[4][4];
    #pragma unroll
    for (int i = 0; i < 4; i++)
        #pragma unroll
        for (int j = 0; j < 4; j++) acc[i][j] = (float4_t){0.f, 0.f, 0.f, 0.f};

    const int srow = lane >> 2;
    const int scol = (lane & 3) * 8;
    ushort_t* lA0 = &As[(wave * 32 + srow) * BKP + scol];
    ushort_t* lB0 = &Bs[(wave * 32 + srow) * BKP + scol];

    for (int kt = 0; kt < KK; kt += BK) {
        __syncthreads();
        stage8(0,   Xg, (long)(m0 + wave * 32 + srow), kt + scol, lA0);
        stage8(0,   Xg, (long)(m0 + wave * 32 + srow + 16), kt + scol, lA0 + 16 * BKP);
        stage8(f32, Bg, (long)(n0 + wave * 32 + srow), kt + scol, lB0);
        stage8(f32, Bg, (long)(n0 + wave * 32 + srow + 16), kt + scol, lB0 + 16 * BKP);
        __syncthreads();
        short8 af[4], bfr[4];
        #pragma unroll
        for (int mt = 0; mt < 4; mt++)
            af[mt] = *(const short8*)&As[(wm * 64 + mt * 16 + l16) * BKP + quad * 8];
        #pragma unroll
        for (int nt = 0; nt < 4; nt++)
            bfr[nt] = *(const short8*)&Bs[(wn * 64 + nt * 16 + l16) * BKP + quad * 8];
        #pragma unroll
        for (int mt = 0; mt < 4; mt++)
            #pragma unroll
            for (int nt = 0; nt < 4; nt++)
                acc[mt][nt] = __builtin_amdgcn_mfma_f32_16x16x32_bf16(af[mt], bfr[nt], acc[mt][nt], 0, 0, 0);
    }

    float wv[4], bv[4];
    #pragma unroll
    for (int nt = 0; nt < 4; nt++) {
        int n = n0 + wn * 64 + nt * 16 + l16;
        wv[nt] = ldmix(f32, wattn, n);
        bv[nt] = ldmix(f32, b1, n);
    }
    #pragma unroll
    for (int mt = 0; mt < 4; mt++) {
        #pragma unroll
        for (int r = 0; r < 4; r++) {
            int m = m0 + wm * 64 + mt * 16 + quad * 4 + r;
            float s = 0.f;
            #pragma unroll
            for (int nt = 0; nt < 4; nt++) {
                int n = n0 + wn * 64 + nt * 16 + l16;
                float v = acc[mt][nt][r] + bv[nt] + bf2f(Xg[(size_t)m * AA + n]);
                s += fast_tanh(v) * wv[nt];
            }
            s += __shfl_xor(s, 1);
            s += __shfl_xor(s, 2);
            s += __shfl_xor(s, 4);
            s += __shfl_xor(s, 8);
            if (l16 == 0) atomicAdd(&scores[m], s);
        }
    }
}

__global__ void k_softmax(const float* __restrict__ scores,
                          const int* __restrict__ mask,
                          const void* __restrict__ cov,
                          const int* __restrict__ flagp,
                          float* __restrict__ attnw,
                          void* __restrict__ dout) {
    __shared__ float red[4];
    const int f32 = *flagp;
    int b = blockIdx.x, tid = threadIdx.x;
    float v[4];
    #pragma unroll
    for (int i = 0; i < 4; i++) {
        int s = tid + i * 256;
        float sc = scores[b * SS + s];
        if (mask[b * SS + s] == 0) sc = -1e9f;
        v[i] = sc;
    }
    float mx = fmaxf(fmaxf(v[0], v[1]), fmaxf(v[2], v[3]));
    #pragma unroll
    for (int off = 1; off < 64; off <<= 1) mx = fmaxf(mx, __shfl_xor(mx, off));
    if ((tid & 63) == 0) red[tid >> 6] = mx;
    __syncthreads();
    mx = fmaxf(fmaxf(red[0], red[1]), fmaxf(red[2], red[3]));
    __syncthreads();
    float e[4], sum = 0.f;
    #pragma unroll
    for (int i = 0; i < 4; i++) { e[i] = expf(v[i] - mx); sum += e[i]; }
    #pragma unroll
    for (int off = 1; off < 64; off <<= 1) sum += __shfl_xor(sum, off);
    if ((tid & 63) == 0) red[tid >> 6] = sum;
    __syncthreads();
    sum = red[0] + red[1] + red[2] + red[3];
    float inv = 1.0f / sum;
    #pragma unroll
    for (int i = 0; i < 4; i++) {
        int s = tid + i * 256;
        float w = e[i] * inv;
        attnw[b * SS + s] = w;
        stmix(f32, dout, 32768L + (long)b * SS + s, w);
        stmix(f32, dout, 98304L + (long)b * SS + s, ldmix(f32, cov, (long)b * SS + s) + w);
    }
}

__global__ void k_context(const void* __restrict__ enc,
                          const float* __restrict__ attnw,
                          const int* __restrict__ flagp,
                          float* __restrict__ ctx) {
    const int f32 = *flagp;
    int b = blockIdx.x, sc = blockIdx.y;
    int tid = threadIdx.x;
    float a0 = 0.f, a1 = 0.f;
    const float* wrow = attnw + b * SS + sc * 128;
    if (f32) {
        const float* base = (const float*)enc + ((size_t)b * SS + sc * 128) * EE;
        for (int s = 0; s < 128; s++) {
            float w = wrow[s];
            float2_t u = *(const float2_t*)(base + (size_t)s * EE + 2 * tid);
            a0 += w * u[0];
            a1 += w * u[1];
        }
    } else {
        const unsigned int* base = (const unsigned int*)enc + ((size_t)b * SS + sc * 128) * (EE / 2);
        for (int s = 0; s < 128; s++) {
            float w = wrow[s];
            unsigned int u = base[(size_t)s * (EE / 2) + tid];
            a0 += w * bf2f((ushort_t)(u & 0xffff));
            a1 += w * bf2f((ushort_t)(u >> 16));
        }
    }
    atomicAdd(&ctx[b * EE + 2 * tid], a0);
    atomicAdd(&ctx[b * EE + 2 * tid + 1], a1);
}

// ---------------- gate: wave-per-output. grid (A/4, B), 256 thr ----------------
__global__ __launch_bounds__(256)
void k_gate(const float* __restrict__ ctx,
            const void* __restrict__ dec,
            const void* __restrict__ Wg,
            const void* __restrict__ bg,
            const int* __restrict__ flagp,
            void* __restrict__ dout) {
    __shared__ float gin[EE + DD];
    const int f32 = *flagp;
    const int b = blockIdx.y;
    const int tid = threadIdx.x, lane = tid & 63, wave = tid >> 6;
    gin[2 * tid]     = ctx[b * EE + 2 * tid];
    gin[2 * tid + 1] = ctx[b * EE + 2 * tid + 1];
    gin[EE + tid]       = ldmix(f32, dec, (long)b * DD + tid);
    gin[EE + tid + 256] = ldmix(f32, dec, (long)b * DD + tid + 256);
    __syncthreads();
    const int a = blockIdx.x * 4 + wave;
    float s = 0.f;
    if (f32) {
        const float* wr = (const float*)Wg + (size_t)a * (EE + DD) + lane * 16;
        #pragma unroll
        for (int j = 0; j < 16; j++) s += wr[j] * gin[lane * 16 + j];
    } else {
        const ushort_t* wr = (const ushort_t*)Wg + (size_t)a * (EE + DD) + lane * 16;
        short8 w0 = *(const short8*)wr;
        short8 w1 = *(const short8*)(wr + 8);
        #pragma unroll
        for (int j = 0; j < 8; j++) {
            s += bf2f((ushort_t)w0[j]) * gin[lane * 16 + j];
            s += bf2f((ushort_t)w1[j]) * gin[lane * 16 + 8 + j];
        }
    }
    #pragma unroll
    for (int off = 1; off < 64; off <<= 1) s += __shfl_xor(s, off);
    if (lane == 0) {
        float acc = s + ldmix(f32, bg, a);
        float g = 1.f / (1.f + __expf(-acc));
        stmix(f32, dout, (long)b * AA + a, g * ctx[b * EE + a]);
    }
}

extern "C" void kernel_launch(void* const* d_in, const int* in_sizes, int n_in,
                              void* d_out, int out_size, void* d_ws, size_t ws_size,
                              hipStream_t stream) {
    const void* enc   = d_in[0];
    const void* dec   = d_in[1];
    const int*  mask  = (const int*)d_in[2];
    const void* cov   = d_in[3];
    const void* Wenc  = d_in[4];
    const void* Wdec  = d_in[5];
    const void* wattn = d_in[6];
    const void* Wl1   = d_in[7];
    const void* b1    = d_in[8];
    const void* Wcov  = d_in[9];
    const void* Wg    = d_in[10];
    const void* bg    = d_in[11];

    char* ws = (char*)d_ws;
    float*    scores = (float*)ws;                 // 262144 B
    float*    ctx    = (float*)(ws + 262144);      // 131072 B
    float*    attnw  = (float*)(ws + 393216);      // 262144 B
    float*    projd  = (float*)(ws + 655360);      // 131072 B
    int*      flag   = (int*)(ws + 786432);        // 4 B
    ushort_t* feats  = (ushort_t*)(ws + 1048576);  // 67108864 B

    hipMemsetAsync(ws, 0, 393216, stream);
    k_detect<<<1, 256, 0, stream>>>((const ushort_t*)enc, flag);
    k_proj_dec<<<dim3(AA / 4, BB), 256, 0, stream>>>(dec, Wdec, flag, projd);
    k_gemm1<<<dim3(AA / BN, MM / BM), 256, 0, stream>>>(enc, Wenc, projd, cov, Wcov, flag, feats);
    k_gemm2<<<dim3(AA / BN, MM / BM), 256, 0, stream>>>(feats, Wl1, b1, wattn, flag, scores);
    k_softmax<<<BB, 256, 0, stream>>>(scores, mask, cov, flag, attnw, d_out);
    k_context<<<dim3(BB, 8), 256, 0, stream>>>(enc, attnw, flag, ctx);
    k_gate<<<dim3(AA / 4, BB), 256, 0, stream>>>(ctx, dec, Wg, bg, flag, d_out);
}